// Round 1
// baseline (377.508 us; speedup 1.0000x reference)
//
#include <hip/hip_runtime.h>
#include <math.h>

#define SUM_H 224
#define SUM_W 221
#define ROWP  224   // padded row stride (floats) for all gene tables; level offs {0,128,192} are 16B-aligned

// ---------------------------------------------------------------------------
// Kernel 1: per selected gene, build softmax widths + bin locations per level
// and gather the gene's uh row. One wave (64 threads) per gene.
// Tables (row stride ROWP floats):
//   uh_t : uh gathered, natural layout offs {0,128,192}
//   w_t  : widths, level offs {0,128,192}; valid counts {127,63,31}
//   bl_t : bin locations (n edges incl leading 0, trailing forced 1.0),
//          level offs {0,128,192}; counts {128,64,32} (fills the row exactly)
// ---------------------------------------------------------------------------
__global__ __launch_bounds__(64) void gene_tables_kernel(
    const float* __restrict__ heights_weight,
    const float* __restrict__ widths_weight,
    const int*   __restrict__ genes_oi,
    float* __restrict__ uh_t,
    float* __restrict__ w_t,
    float* __restrict__ bl_t,
    int n_genes)
{
    int g = blockIdx.x;
    if (g >= n_genes) return;
    int gi = genes_oi[g];
    int l  = threadIdx.x;

    // gather uh row (coalesced)
    {
        const float* src = heights_weight + (size_t)gi * SUM_H;
        float*       dst = uh_t + (size_t)g * ROWP;
        for (int j = l; j < SUM_H; j += 64) dst[j] = src[j];
    }

    const float* wsrc  = widths_weight + (size_t)gi * SUM_W;
    float*       wdst  = w_t  + (size_t)g * ROWP;
    float*       bldst = bl_t + (size_t)g * ROWP;

    const int ns[3]   = {128, 64, 32};
    const int woff[3] = {0, 127, 190};   // offsets inside the 221-wide source row
    const int toff[3] = {0, 128, 192};   // offsets inside padded table rows

    for (int lev = 0; lev < 3; lev++) {
        int m  = ns[lev] - 1;            // number of widths
        int j0 = 2 * l, j1 = 2 * l + 1;  // pair layout: lane l holds elems 2l,2l+1
        float u0 = (j0 < m) ? wsrc[woff[lev] + j0] : -1e30f;
        float u1 = (j1 < m) ? wsrc[woff[lev] + j1] : -1e30f;
        float mx = fmaxf(u0, u1);
        #pragma unroll
        for (int msk = 32; msk >= 1; msk >>= 1)
            mx = fmaxf(mx, __shfl_xor(mx, msk, 64));
        float e0 = (j0 < m) ? __expf(u0 - mx) : 0.f;
        float e1 = (j1 < m) ? __expf(u1 - mx) : 0.f;
        float local = e0 + e1;
        float incl  = local;
        #pragma unroll
        for (int off = 1; off < 64; off <<= 1) {
            float t = __shfl_up(incl, off, 64);
            if (l >= off) incl += t;
        }
        float total = __shfl(incl, 63, 64);
        float inv   = 1.0f / total;
        float excl  = incl - local;
        if (j0 < m) wdst[toff[lev] + j0] = e0 * inv;
        if (j1 < m) wdst[toff[lev] + j1] = e1 * inv;
        float c0 = (excl + e0) * inv;        // normalized cumsum at j0
        float c1 = (excl + e0 + e1) * inv;   // at j1
        if (j0 <= m - 2) bldst[toff[lev] + j0 + 1] = c0;
        if (j1 <= m - 2) bldst[toff[lev] + j1 + 1] = c1;
        if (l == 0) {
            bldst[toff[lev]]     = 0.0f;  // leading pad
            bldst[toff[lev] + m] = 1.0f;  // forced last edge
        }
    }
}

// ---------------------------------------------------------------------------
// Kernel 2: 16 lanes per point. Lane e handles 4-element chunks c = ch*64+4e.
// ---------------------------------------------------------------------------
template<int N>
__device__ inline void level_step(
    const float* __restrict__ dh,   // delta row + level offset
    const float* __restrict__ uh,   // gene uh row + level offset
    const float* __restrict__ bl,   // gene bin locations + level offset (N entries)
    const float* __restrict__ wt,   // gene widths + level offset (N-1 valid)
    int e, float& x, float& lad)
{
    constexpr int NCH = (N + 63) / 64;            // chunks per lane: 2 for 128, else 1
    constexpr int ACT = (N >= 64) ? 16 : (N / 4); // active sub-lanes

    float s[NCH][4];
    int cnt = 0;
    #pragma unroll
    for (int ch = 0; ch < NCH; ch++) {
        int c = ch * 64 + 4 * e;
        bool act = (e < ACT);
        if (act) {
            float4 dh4 = *reinterpret_cast<const float4*>(dh + c);
            float4 uh4 = *reinterpret_cast<const float4*>(uh + c);
            float4 bl4 = *reinterpret_cast<const float4*>(bl + c);
            float4 w4  = *reinterpret_cast<const float4*>(wt + c);
            bool hx = (c + 4) <= (N - 1);
            float dhx = hx ? dh[c + 4] : 0.f;
            float uhx = hx ? uh[c + 4] : 0.f;
            float E0 = __expf(uh4.x + dh4.x);
            float E1 = __expf(uh4.y + dh4.y);
            float E2 = __expf(uh4.z + dh4.z);
            float E3 = __expf(uh4.w + dh4.w);
            float E4 = __expf(uhx + dhx);
            cnt += (x >= bl4.x) + (x >= bl4.y) + (x >= bl4.z) + (x >= bl4.w);
            s[ch][0] = 0.5f * (E0 + E1) * w4.x;
            s[ch][1] = 0.5f * (E1 + E2) * w4.y;
            s[ch][2] = 0.5f * (E2 + E3) * w4.z;
            s[ch][3] = ((c + 3) <= (N - 2)) ? 0.5f * (E3 + E4) * w4.w : 0.f;
        } else {
            s[ch][0] = s[ch][1] = s[ch][2] = s[ch][3] = 0.f;
        }
    }

    // phase 1: count of edges <= x  ->  bin index (exact reference semantics)
    #pragma unroll
    for (int msk = 8; msk >= 1; msk >>= 1)
        cnt += __shfl_xor(cnt, msk, 16);
    int idx = cnt - 1;
    if (idx > N - 2) idx = N - 2;   // cnt >= 1 always since bl[0]=0 <= x

    // phase 2: total area + partial area strictly below bin idx
    float area = 0.f, part = 0.f;
    #pragma unroll
    for (int ch = 0; ch < NCH; ch++) {
        int c = ch * 64 + 4 * e;
        #pragma unroll
        for (int k = 0; k < 4; k++) {
            area += s[ch][k];
            part += ((c + k) < idx) ? s[ch][k] : 0.f;
        }
    }
    #pragma unroll
    for (int msk = 8; msk >= 1; msk >>= 1) {
        area += __shfl_xor(area, msk, 16);
        part += __shfl_xor(part, msk, 16);
    }

    // gene/point values at the bin (wave-group-uniform, L1-hot)
    float in_bl = bl[idx];
    float w     = wt[idx];
    float El    = __expf(uh[idx]     + dh[idx]);
    float Er    = __expf(uh[idx + 1] + dh[idx + 1]);

    float inv   = 1.0f / area;
    float hl    = El * inv;
    float hr    = Er * inv;
    float icdf  = part * inv;
    float alpha = (x - in_bl) / w;
    float dhh   = hr - hl;
    float out   = (0.5f * dhh * w) * alpha * alpha + (hl * w) * alpha + icdf;
    lad += __logf(alpha * dhh + hl);
    x = fminf(fmaxf(out, 0.f), 1.f);
}

__global__ __launch_bounds__(256) void spline_kernel(
    const float* __restrict__ x_in,
    const float* __restrict__ delta,
    const int*   __restrict__ lgx,
    const float* __restrict__ uh_t,
    const float* __restrict__ w_t,
    const float* __restrict__ bl_t,
    float* __restrict__ out,
    float* __restrict__ lad_out,
    int n_points)
{
    int tid = blockIdx.x * blockDim.x + threadIdx.x;
    int p = tid >> 4;       // 16 lanes per point
    int e = tid & 15;
    if (p >= n_points) return;

    int   g   = lgx[p];
    float x   = x_in[p];
    float lad = 0.f;

    const float* dh = delta + (size_t)p * SUM_H;
    const float* uh = uh_t + (size_t)g * ROWP;
    const float* bl = bl_t + (size_t)g * ROWP;
    const float* wt = w_t  + (size_t)g * ROWP;

    level_step<128>(dh,       uh,       bl,       wt,       e, x, lad);
    level_step<64> (dh + 128, uh + 128, bl + 128, wt + 128, e, x, lad);
    level_step<32> (dh + 192, uh + 192, bl + 192, wt + 192, e, x, lad);

    if (e == 0) {
        out[p]     = x;
        lad_out[p] = lad;
    }
}

extern "C" void kernel_launch(void* const* d_in, const int* in_sizes, int n_in,
                              void* d_out, int out_size, void* d_ws, size_t ws_size,
                              hipStream_t stream)
{
    const float* x        = (const float*)d_in[0];
    const float* delta    = (const float*)d_in[1];
    const float* hw       = (const float*)d_in[2];
    const float* ww       = (const float*)d_in[3];
    const int*   genes_oi = (const int*)  d_in[4];
    const int*   lgx      = (const int*)  d_in[5];

    int n_points   = in_sizes[0];
    int n_genes_oi = in_sizes[4];

    float* uh_t = (float*)d_ws;
    float* w_t  = uh_t + (size_t)n_genes_oi * ROWP;
    float* bl_t = w_t  + (size_t)n_genes_oi * ROWP;

    hipLaunchKernelGGL(gene_tables_kernel, dim3(n_genes_oi), dim3(64), 0, stream,
                       hw, ww, genes_oi, uh_t, w_t, bl_t, n_genes_oi);

    const int threads = 256;
    const int ppb     = threads / 16;
    const int blocks  = (n_points + ppb - 1) / ppb;
    hipLaunchKernelGGL(spline_kernel, dim3(blocks), dim3(threads), 0, stream,
                       x, delta, lgx, uh_t, w_t, bl_t,
                       (float*)d_out, (float*)d_out + n_points, n_points);
}

// Round 2
// 351.397 us; speedup vs baseline: 1.0743x; 1.0743x over previous
//
#include <hip/hip_runtime.h>
#include <math.h>

#define SUM_H 224
#define SUM_W 221
#define ROWP  224   // padded row stride (floats); level offsets {0,128,192} are 16B-aligned

// ---------------------------------------------------------------------------
// Kernel 1: per selected gene, softmax widths (stored pre-scaled by 0.5) and
// bin locations per level. One wave per gene. Pad slots zeroed.
//   wh_t : 0.5 * softmax width, level offs {0,128,192}; valid {127,63,31}
//   bl_t : bin edges (leading 0, trailing forced 1.0), offs {0,128,192},
//          counts {128,64,32} (fills the 224-row exactly)
// ---------------------------------------------------------------------------
__global__ __launch_bounds__(64) void gene_tables_kernel(
    const float* __restrict__ widths_weight,
    const int*   __restrict__ genes_oi,
    float* __restrict__ wh_t,
    float* __restrict__ bl_t,
    int n_genes)
{
    int g = blockIdx.x;
    if (g >= n_genes) return;
    int gi = genes_oi[g];
    int l  = threadIdx.x;

    const float* wsrc  = widths_weight + (size_t)gi * SUM_W;
    float*       wdst  = wh_t + (size_t)g * ROWP;
    float*       bldst = bl_t + (size_t)g * ROWP;

    const int ns[3]   = {128, 64, 32};
    const int woff[3] = {0, 127, 190};   // offsets inside the 221-wide source row
    const int toff[3] = {0, 128, 192};   // offsets inside padded table rows

    for (int lev = 0; lev < 3; lev++) {
        int m  = ns[lev] - 1;            // number of widths
        int j0 = 2 * l, j1 = 2 * l + 1;  // lane l owns elems 2l, 2l+1
        float u0 = (j0 < m) ? wsrc[woff[lev] + j0] : -1e30f;
        float u1 = (j1 < m) ? wsrc[woff[lev] + j1] : -1e30f;
        float mx = fmaxf(u0, u1);
        #pragma unroll
        for (int msk = 32; msk >= 1; msk >>= 1)
            mx = fmaxf(mx, __shfl_xor(mx, msk, 64));
        float e0 = (j0 < m) ? __expf(u0 - mx) : 0.f;
        float e1 = (j1 < m) ? __expf(u1 - mx) : 0.f;
        float local = e0 + e1;
        float incl  = local;
        #pragma unroll
        for (int off = 1; off < 64; off <<= 1) {
            float t = __shfl_up(incl, off, 64);
            if (l >= off) incl += t;
        }
        float total = __shfl(incl, 63, 64);
        float inv   = 1.0f / total;
        float excl  = incl - local;
        if (j0 < m) wdst[toff[lev] + j0] = 0.5f * e0 * inv;
        if (j1 < m) wdst[toff[lev] + j1] = 0.5f * e1 * inv;
        float c0 = (excl + e0) * inv;
        float c1 = (excl + e0 + e1) * inv;
        if (j0 <= m - 2) bldst[toff[lev] + j0 + 1] = c0;
        if (j1 <= m - 2) bldst[toff[lev] + j1 + 1] = c1;
        if (l == 0) {
            bldst[toff[lev]]     = 0.0f;
            bldst[toff[lev] + m] = 1.0f;
        }
    }
    if (l == 0) { wdst[127] = 0.f; wdst[191] = 0.f; wdst[223] = 0.f; }
}

// ---------------------------------------------------------------------------
// Kernel 2: 16 lanes per point; lane e owns contiguous elems [K*e, K*e+K).
// ---------------------------------------------------------------------------
template<int K>
struct Lvl {
    float E[K + 1];   // fetch: uh staged here, then E = exp(uh+dh); E[K] = neighbor
    float bl[K];
    float wh[K];      // 0.5 * width
    float s[K];       // fetch: dh staged here, then trapezoid masses
    float bln;        // neighbor lane's bl[0]
    float area;       // group-total (uniform across the 16 lanes)
};

template<int K>
__device__ __forceinline__ void lvl_fetch(const float* __restrict__ dh,
                                          const float* __restrict__ uh,
                                          const float* __restrict__ blp,
                                          const float* __restrict__ whp,
                                          int e, Lvl<K>& L)
{
    const int j = K * e;
    if constexpr (K == 8) {
        *(float4*)&L.E[0]  = *(const float4*)(uh  + j);
        *(float4*)&L.E[4]  = *(const float4*)(uh  + j + 4);
        *(float4*)&L.s[0]  = *(const float4*)(dh  + j);
        *(float4*)&L.s[4]  = *(const float4*)(dh  + j + 4);
        *(float4*)&L.bl[0] = *(const float4*)(blp + j);
        *(float4*)&L.bl[4] = *(const float4*)(blp + j + 4);
        *(float4*)&L.wh[0] = *(const float4*)(whp + j);
        *(float4*)&L.wh[4] = *(const float4*)(whp + j + 4);
    } else if constexpr (K == 4) {
        *(float4*)&L.E[0]  = *(const float4*)(uh  + j);
        *(float4*)&L.s[0]  = *(const float4*)(dh  + j);
        *(float4*)&L.bl[0] = *(const float4*)(blp + j);
        *(float4*)&L.wh[0] = *(const float4*)(whp + j);
    } else {
        *(float2*)&L.E[0]  = *(const float2*)(uh  + j);
        *(float2*)&L.s[0]  = *(const float2*)(dh  + j);
        *(float2*)&L.bl[0] = *(const float2*)(blp + j);
        *(float2*)&L.wh[0] = *(const float2*)(whp + j);
    }
}

template<int K>
__device__ __forceinline__ void lvl_finish(int e, Lvl<K>& L)
{
    #pragma unroll
    for (int k = 0; k < K; k++) L.E[k] = __expf(L.E[k] + L.s[k]);
    L.E[K] = __shfl_down(L.E[0], 1, 16);
    L.bln  = __shfl_down(L.bl[0], 1, 16);
    #pragma unroll
    for (int k = 0; k < K; k++) L.s[k] = (L.E[k] + L.E[k + 1]) * L.wh[k];
    if (e == 15) L.s[K - 1] = 0.f;   // mass N-1 does not exist
    float a = 0.f;
    #pragma unroll
    for (int k = 0; k < K; k++) a += L.s[k];
    #pragma unroll
    for (int m = 8; m >= 1; m >>= 1) a += __shfl_xor(a, m, 16);
    L.area = a;
}

template<int N, int K>
__device__ __forceinline__ void lvl_apply(const Lvl<K>& L, float& x, float& lad)
{
    constexpr int LOGK = (K == 8) ? 3 : (K == 4) ? 2 : 1;
    int   cnt  = 0;
    float part = 0.f;
    #pragma unroll
    for (int k = 0; k < K; k++) cnt += (x >= L.bl[k]) ? 1 : 0;
    #pragma unroll
    for (int k = 0; k < K - 1; k++) part += (x >= L.bl[k + 1]) ? L.s[k] : 0.f;
    part += (x >= L.bln) ? L.s[K - 1] : 0.f;   // lane15: s[K-1]==0, junk pred harmless

    #pragma unroll
    for (int m = 8; m >= 1; m >>= 1) {
        cnt  += __shfl_xor(cnt,  m, 16);
        part += __shfl_xor(part, m, 16);
    }
    int idx = cnt - 1;                 // cnt >= 1 since bl[0]=0 <= x
    if (idx > N - 2) idx = N - 2;      // x==1.0 case; out-clip absorbs part's off-by-one
    const int owner = idx >> LOGK;
    const int slot  = idx & (K - 1);

    float sE = L.E[0], sE1 = L.E[1], sB = L.bl[0], sW = L.wh[0];
    #pragma unroll
    for (int jj = 1; jj < K; jj++) {
        bool m = (slot == jj);
        sE  = m ? L.E[jj]     : sE;
        sE1 = m ? L.E[jj + 1] : sE1;
        sB  = m ? L.bl[jj]    : sB;
        sW  = m ? L.wh[jj]    : sW;
    }
    float hlr = __shfl(sE,  owner, 16);
    float hrr = __shfl(sE1, owner, 16);
    float inb = __shfl(sB,  owner, 16);
    float whs = __shfl(sW,  owner, 16);

    float inva  = __builtin_amdgcn_rcpf(L.area);
    float hl    = hlr * inva;
    float dhh   = (hrr - hlr) * inva;
    float icdf  = part * inva;
    float alpha = (x - inb) * __builtin_amdgcn_rcpf(whs + whs);
    // a = wh*dhh, b = 2*hl*wh; out = (a*alpha + b)*alpha + icdf
    float outv  = fmaf(fmaf(whs, dhh * alpha, (hl + hl) * whs), alpha, icdf);
    lad += __logf(fmaf(alpha, dhh, hl));
    x = __builtin_amdgcn_fmed3f(outv, 0.0f, 1.0f);
}

__global__ __launch_bounds__(256) void spline_kernel(
    const float* __restrict__ x_in,
    const float* __restrict__ delta,
    const int*   __restrict__ lgx,
    const int*   __restrict__ genes_oi,
    const float* __restrict__ heights_weight,
    const float* __restrict__ wh_t,
    const float* __restrict__ bl_t,
    float* __restrict__ out,
    float* __restrict__ lad_out,
    int n_points)
{
    int tid = blockIdx.x * blockDim.x + threadIdx.x;
    int p = tid >> 4;
    int e = tid & 15;
    if (p >= n_points) return;

    int g  = lgx[p];
    int gi = genes_oi[g];
    const float* dh = delta          + (size_t)p  * SUM_H;
    const float* uh = heights_weight + (size_t)gi * SUM_H;  // rows are 224 = ROWP
    const float* bl = bl_t + (size_t)g * ROWP;
    const float* wh = wh_t + (size_t)g * ROWP;

    Lvl<8> L0; Lvl<4> L1; Lvl<2> L2;
    // issue ALL global loads first (deep vmcnt overlap), then compute
    lvl_fetch<8>(dh,       uh,       bl,       wh,       e, L0);
    lvl_fetch<4>(dh + 128, uh + 128, bl + 128, wh + 128, e, L1);
    lvl_fetch<2>(dh + 192, uh + 192, bl + 192, wh + 192, e, L2);
    float x   = x_in[p];
    float lad = 0.f;
    lvl_finish<8>(e, L0);
    lvl_finish<4>(e, L1);
    lvl_finish<2>(e, L2);

    // serial x-chain: registers + cross-lane only, no memory
    lvl_apply<128, 8>(L0, x, lad);
    lvl_apply<64,  4>(L1, x, lad);
    lvl_apply<32,  2>(L2, x, lad);

    if (e == 0) {
        out[p]     = x;
        lad_out[p] = lad;
    }
}

extern "C" void kernel_launch(void* const* d_in, const int* in_sizes, int n_in,
                              void* d_out, int out_size, void* d_ws, size_t ws_size,
                              hipStream_t stream)
{
    const float* x        = (const float*)d_in[0];
    const float* delta    = (const float*)d_in[1];
    const float* hw       = (const float*)d_in[2];
    const float* ww       = (const float*)d_in[3];
    const int*   genes_oi = (const int*)  d_in[4];
    const int*   lgx      = (const int*)  d_in[5];

    int n_points   = in_sizes[0];
    int n_genes_oi = in_sizes[4];

    float* wh_t = (float*)d_ws;
    float* bl_t = wh_t + (size_t)n_genes_oi * ROWP;

    hipLaunchKernelGGL(gene_tables_kernel, dim3(n_genes_oi), dim3(64), 0, stream,
                       ww, genes_oi, wh_t, bl_t, n_genes_oi);

    const int threads = 256;
    const int ppb     = threads / 16;
    const int blocks  = (n_points + ppb - 1) / ppb;
    hipLaunchKernelGGL(spline_kernel, dim3(blocks), dim3(threads), 0, stream,
                       x, delta, lgx, genes_oi, hw, wh_t, bl_t,
                       (float*)d_out, (float*)d_out + n_points, n_points);
}

// Round 3
// 328.417 us; speedup vs baseline: 1.1495x; 1.0700x over previous
//
#include <hip/hip_runtime.h>
#include <math.h>

#define SUM_H 224
#define SUM_W 221
#define ROWP  224   // padded row stride (floats); level offsets {0,128,192} are 16B-aligned

// ---------------------------------------------------------------------------
// Kernel 1: per selected gene, softmax widths -> bin-edge table only.
//   bl_t : bin edges (leading 0, trailing forced 1.0), level offs {0,128,192},
//          counts {128,64,32} (fills the 224-float row exactly).
// Widths are NOT stored; the spline kernel derives w = bl[k+1]-bl[k].
// ---------------------------------------------------------------------------
__global__ __launch_bounds__(64) void gene_tables_kernel(
    const float* __restrict__ widths_weight,
    const int*   __restrict__ genes_oi,
    float* __restrict__ bl_t,
    int n_genes)
{
    int g = blockIdx.x;
    if (g >= n_genes) return;
    int gi = genes_oi[g];
    int l  = threadIdx.x;

    const float* wsrc  = widths_weight + (size_t)gi * SUM_W;
    float*       bldst = bl_t + (size_t)g * ROWP;

    const int ns[3]   = {128, 64, 32};
    const int woff[3] = {0, 127, 190};   // offsets inside the 221-wide source row
    const int toff[3] = {0, 128, 192};   // offsets inside padded table rows

    for (int lev = 0; lev < 3; lev++) {
        int m  = ns[lev] - 1;            // number of widths
        int j0 = 2 * l, j1 = 2 * l + 1;  // lane l owns elems 2l, 2l+1
        float u0 = (j0 < m) ? wsrc[woff[lev] + j0] : -1e30f;
        float u1 = (j1 < m) ? wsrc[woff[lev] + j1] : -1e30f;
        float mx = fmaxf(u0, u1);
        #pragma unroll
        for (int msk = 32; msk >= 1; msk >>= 1)
            mx = fmaxf(mx, __shfl_xor(mx, msk, 64));
        float e0 = (j0 < m) ? __expf(u0 - mx) : 0.f;
        float e1 = (j1 < m) ? __expf(u1 - mx) : 0.f;
        float local = e0 + e1;
        float incl  = local;
        #pragma unroll
        for (int off = 1; off < 64; off <<= 1) {
            float t = __shfl_up(incl, off, 64);
            if (l >= off) incl += t;
        }
        float total = __shfl(incl, 63, 64);
        float inv   = 1.0f / total;
        float excl  = incl - local;
        float c0 = (excl + e0) * inv;
        float c1 = (excl + e0 + e1) * inv;
        if (j0 <= m - 2) bldst[toff[lev] + j0 + 1] = c0;
        if (j1 <= m - 2) bldst[toff[lev] + j1 + 1] = c1;
        if (l == 0) {
            bldst[toff[lev]]     = 0.0f;
            bldst[toff[lev] + m] = 1.0f;
        }
    }
}

// ---------------------------------------------------------------------------
// DPP 16-lane rotate-reductions (a DPP "row" == our 16-lane point group).
// row_ror:n ctrl = 0x120 | n.
// ---------------------------------------------------------------------------
template<int CTRL>
__device__ __forceinline__ float dppf(float v) {
    return __builtin_bit_cast(float,
        __builtin_amdgcn_update_dpp(0, __builtin_bit_cast(int, v), CTRL, 0xF, 0xF, true));
}
template<int CTRL>
__device__ __forceinline__ int dppi(int v) {
    return __builtin_amdgcn_update_dpp(0, v, CTRL, 0xF, 0xF, true);
}
__device__ __forceinline__ float row16_sum(float v) {
    v += dppf<0x121>(v);
    v += dppf<0x122>(v);
    v += dppf<0x124>(v);
    v += dppf<0x128>(v);
    return v;
}
__device__ __forceinline__ int row16_sum_i(int v) {
    v += dppi<0x121>(v);
    v += dppi<0x122>(v);
    v += dppi<0x124>(v);
    v += dppi<0x128>(v);
    return v;
}

// ---------------------------------------------------------------------------
// Kernel 2: 16 lanes per point; lane e owns contiguous elems [K*e, K*e+K).
// ---------------------------------------------------------------------------
template<int K>
struct Lvl {
    float E[K + 1];   // staged uh, then E = exp(uh+dh); E[K] = neighbor's E[0]
    float bl[K];      // bin edges owned by this lane
    float wh[K];      // 0.5*width, derived from bl diffs
    float s[K];       // staged dh, then trapezoid masses
    float bln;        // neighbor lane's bl[0]
    float inva;       // 1/area   (uniform across group)
    float larea;      // log(area)
};

template<int K>
__device__ __forceinline__ void lvl_fetch(const float* __restrict__ dh,
                                          const float* __restrict__ uh,
                                          const float* __restrict__ blp,
                                          int e, Lvl<K>& L)
{
    const int j = K * e;
    if constexpr (K == 8) {
        *(float4*)&L.E[0]  = *(const float4*)(uh  + j);
        *(float4*)&L.E[4]  = *(const float4*)(uh  + j + 4);
        *(float4*)&L.s[0]  = *(const float4*)(dh  + j);
        *(float4*)&L.s[4]  = *(const float4*)(dh  + j + 4);
        *(float4*)&L.bl[0] = *(const float4*)(blp + j);
        *(float4*)&L.bl[4] = *(const float4*)(blp + j + 4);
    } else if constexpr (K == 4) {
        *(float4*)&L.E[0]  = *(const float4*)(uh  + j);
        *(float4*)&L.s[0]  = *(const float4*)(dh  + j);
        *(float4*)&L.bl[0] = *(const float4*)(blp + j);
    } else {
        *(float2*)&L.E[0]  = *(const float2*)(uh  + j);
        *(float2*)&L.s[0]  = *(const float2*)(dh  + j);
        *(float2*)&L.bl[0] = *(const float2*)(blp + j);
    }
}

template<int K>
__device__ __forceinline__ void lvl_finish(int e, Lvl<K>& L)
{
    L.bln = __shfl_down(L.bl[0], 1, 16);          // junk at e==15, masked below
    #pragma unroll
    for (int k = 0; k < K; k++) L.E[k] = __expf(L.E[k] + L.s[k]);
    L.E[K] = __shfl_down(L.E[0], 1, 16);          // junk at e==15, masked below
    #pragma unroll
    for (int k = 0; k < K - 1; k++) L.wh[k] = 0.5f * (L.bl[k + 1] - L.bl[k]);
    L.wh[K - 1] = 0.5f * (L.bln - L.bl[K - 1]);
    #pragma unroll
    for (int k = 0; k < K; k++) L.s[k] = (L.E[k] + L.E[k + 1]) * L.wh[k];
    if (e == 15) L.s[K - 1] = 0.f;                // mass N-1 does not exist
    float a = 0.f;
    #pragma unroll
    for (int k = 0; k < K; k++) a += L.s[k];
    a = row16_sum(a);
    L.inva  = __builtin_amdgcn_rcpf(a);
    L.larea = __logf(a);
}

template<int N, int K>
__device__ __forceinline__ void lvl_apply(const Lvl<K>& L, float& x, float& lad)
{
    constexpr int LOGK = (K == 8) ? 3 : (K == 4) ? 2 : 1;
    int   cnt  = 0;
    float part = 0.f;
    #pragma unroll
    for (int k = 0; k < K; k++) cnt += (x >= L.bl[k]) ? 1 : 0;
    #pragma unroll
    for (int k = 0; k < K - 1; k++) part += (x >= L.bl[k + 1]) ? L.s[k] : 0.f;
    part += (x >= L.bln) ? L.s[K - 1] : 0.f;      // e15: s[K-1]==0, junk pred harmless

    cnt  = row16_sum_i(cnt);
    part = row16_sum(part);

    int idx = cnt - 1;                 // cnt >= 1 since bl[0]=0 <= x
    if (idx > N - 2) idx = N - 2;      // x==1.0; out-clip absorbs part's off-by-one
    const int owner = idx >> LOGK;
    const int slot  = idx & (K - 1);

    float sE = L.E[0], sE1 = L.E[1], sB = L.bl[0], sW = L.wh[0];
    #pragma unroll
    for (int jj = 1; jj < K; jj++) {
        bool m = (slot == jj);
        sE  = m ? L.E[jj]     : sE;
        sE1 = m ? L.E[jj + 1] : sE1;
        sB  = m ? L.bl[jj]    : sB;
        sW  = m ? L.wh[jj]    : sW;
    }
    float El  = __shfl(sE,  owner, 16);
    float Er  = __shfl(sE1, owner, 16);
    float inb = __shfl(sB,  owner, 16);
    float whs = __shfl(sW,  owner, 16);

    float dE    = Er - El;
    float alpha = (x - inb) * __builtin_amdgcn_rcpf(whs + whs);
    // raw-unit poly: alpha^2*(dE*whs) + alpha*(2*El*whs) + part, then * 1/area
    float poly  = fmaf(fmaf(whs * dE, alpha, (El + El) * whs), alpha, part);
    float outv  = poly * L.inva;
    lad += __logf(fmaf(alpha, dE, El)) - L.larea;
    x = __builtin_amdgcn_fmed3f(outv, 0.0f, 1.0f);
}

__global__ __launch_bounds__(256) void spline_kernel(
    const float* __restrict__ x_in,
    const float* __restrict__ delta,
    const int*   __restrict__ lgx,
    const int*   __restrict__ genes_oi,
    const float* __restrict__ heights_weight,
    const float* __restrict__ bl_t,
    float* __restrict__ out,
    float* __restrict__ lad_out,
    int n_points)
{
    int tid = blockIdx.x * blockDim.x + threadIdx.x;
    int p = tid >> 4;
    int e = tid & 15;
    if (p >= n_points) return;

    int g  = lgx[p];
    int gi = genes_oi[g];
    const float* dh = delta          + (size_t)p  * SUM_H;
    const float* uh = heights_weight + (size_t)gi * SUM_H;  // rows are 224 = ROWP
    const float* bl = bl_t + (size_t)g * ROWP;

    Lvl<8> L0; Lvl<4> L1; Lvl<2> L2;
    // staggered: L0+L1 loads in flight, finish0, then L2 loads, ...
    lvl_fetch<8>(dh,       uh,       bl,       e, L0);
    lvl_fetch<4>(dh + 128, uh + 128, bl + 128, e, L1);
    float x   = x_in[p];
    float lad = 0.f;
    lvl_finish<8>(e, L0);
    lvl_fetch<2>(dh + 192, uh + 192, bl + 192, e, L2);
    lvl_finish<4>(e, L1);
    lvl_apply<128, 8>(L0, x, lad);
    lvl_finish<2>(e, L2);
    lvl_apply<64,  4>(L1, x, lad);
    lvl_apply<32,  2>(L2, x, lad);

    if (e == 0) {
        out[p]     = x;
        lad_out[p] = lad;
    }
}

extern "C" void kernel_launch(void* const* d_in, const int* in_sizes, int n_in,
                              void* d_out, int out_size, void* d_ws, size_t ws_size,
                              hipStream_t stream)
{
    const float* x        = (const float*)d_in[0];
    const float* delta    = (const float*)d_in[1];
    const float* hw       = (const float*)d_in[2];
    const float* ww       = (const float*)d_in[3];
    const int*   genes_oi = (const int*)  d_in[4];
    const int*   lgx      = (const int*)  d_in[5];

    int n_points   = in_sizes[0];
    int n_genes_oi = in_sizes[4];

    float* bl_t = (float*)d_ws;

    hipLaunchKernelGGL(gene_tables_kernel, dim3(n_genes_oi), dim3(64), 0, stream,
                       ww, genes_oi, bl_t, n_genes_oi);

    const int threads = 256;
    const int ppb     = threads / 16;
    const int blocks  = (n_points + ppb - 1) / ppb;
    hipLaunchKernelGGL(spline_kernel, dim3(blocks), dim3(threads), 0, stream,
                       x, delta, lgx, genes_oi, hw, bl_t,
                       (float*)d_out, (float*)d_out + n_points, n_points);
}